// Round 1
// baseline (709.992 us; speedup 1.0000x reference)
//
#include <hip/hip_runtime.h>

#define N_NODES 40000
#define N_EDGES 640000
#define N_GRAPHS 64

static inline int cdiv(long long a, int b) { return (int)((a + b - 1) / b); }

// ---------------- edge aggregation: agg[dst] += ew * x[src] ----------------
// Group of F=(1<<LOGF) lanes per edge, lane = feature index. Contiguous row
// reads and contiguous atomic addresses within each lane group.
template<int LOGF, int FIN>
__global__ void edge_agg(const float* __restrict__ x,
                         const int* __restrict__ src,
                         const int* __restrict__ dst,
                         const float* __restrict__ ew,
                         float* __restrict__ agg) {
    long long tid = (long long)blockIdx.x * blockDim.x + threadIdx.x;
    int e = (int)(tid >> LOGF);
    if (e >= N_EDGES) return;
    int f = (int)(tid & ((1 << LOGF) - 1));
    if (f < FIN) {
        int s = src[e];
        int d = dst[e];
        float w = ew[e];
        atomicAdd(&agg[(long long)d * FIN + f], w * x[(long long)s * FIN + f]);
    }
}

// ---------------- node update: hout = agg @ w_rel + b_rel + hin @ w_root ----
template<int FIN, int FOUT, int LOGFO>
__global__ void node_update(const float* __restrict__ agg,
                            const float* __restrict__ hin,
                            const float* __restrict__ w_rel,
                            const float* __restrict__ b_rel,
                            const float* __restrict__ w_root,
                            float* __restrict__ hout) {
    long long tid = (long long)blockIdx.x * blockDim.x + threadIdx.x;
    int n = (int)(tid >> LOGFO);
    if (n >= N_NODES) return;
    int fo = (int)(tid & (FOUT - 1));
    float acc = b_rel[fo];
    #pragma unroll
    for (int fi = 0; fi < FIN; ++fi)
        acc += agg[(long long)n * FIN + fi] * w_rel[fi * FOUT + fo];
    #pragma unroll
    for (int fi = 0; fi < FIN; ++fi)
        acc += hin[(long long)n * FIN + fi] * w_root[fi * FOUT + fo];
    hout[(long long)n * FOUT + fo] = acc;
}

// ---------------- pooling: pooled[batch[n]] += h[n]  (batch sorted) --------
// One block = 256-node chunk, 128 threads (one per feature). Running segment
// sum in registers; atomic only at segment boundaries.
__global__ void pool_kernel(const float* __restrict__ h,
                            const int* __restrict__ batch,
                            float* __restrict__ pooled) {
    const int NB = 256;
    int n0 = blockIdx.x * NB;
    if (n0 >= N_NODES) return;
    int n1 = n0 + NB; if (n1 > N_NODES) n1 = N_NODES;
    int f = threadIdx.x;  // 0..127
    float acc = 0.f;
    int cur = batch[n0];
    for (int n = n0; n < n1; ++n) {
        int g = batch[n];
        if (g != cur) {
            atomicAdd(&pooled[cur * 128 + f], acc);
            acc = 0.f;
            cur = g;
        }
        acc += h[(long long)n * 128 + f];
    }
    atomicAdd(&pooled[cur * 128 + f], acc);
}

// ---------------- classifier: out = pooled @ w_lin + b_lin -----------------
__global__ void final_kernel(const float* __restrict__ pooled,
                             const float* __restrict__ w_lin,
                             const float* __restrict__ b_lin,
                             float* __restrict__ out) {
    int tid = threadIdx.x;  // 128 threads: (graph, class)
    int g = tid >> 1;
    int c = tid & 1;
    float acc = b_lin[c];
    #pragma unroll 8
    for (int fi = 0; fi < 128; ++fi)
        acc += pooled[g * 128 + fi] * w_lin[fi * 2 + c];
    out[g * 2 + c] = acc;
}

extern "C" void kernel_launch(void* const* d_in, const int* in_sizes, int n_in,
                              void* d_out, int out_size, void* d_ws, size_t ws_size,
                              hipStream_t stream) {
    const float* x     = (const float*)d_in[0];
    const int*   ei    = (const int*)d_in[1];
    const float* ea    = (const float*)d_in[2];
    const int*   batch = (const int*)d_in[3];
    const int* src = ei;
    const int* dst = ei + N_EDGES;

    const float* w_rel[5], *b_rel[5], *w_root[5];
    for (int i = 0; i < 5; ++i) {
        w_rel[i]  = (const float*)d_in[4 + 3 * i];
        b_rel[i]  = (const float*)d_in[5 + 3 * i];
        w_root[i] = (const float*)d_in[6 + 3 * i];
    }
    const float* w_lin = (const float*)d_in[19];
    const float* b_lin = (const float*)d_in[20];
    float* out = (float*)d_out;

    // workspace layout (floats): hA[40000*128] | hB[40000*128] | agg[40000*64] | pooled[64*128]
    float* hA     = (float*)d_ws;
    float* hB     = hA + (long long)N_NODES * 128;
    float* agg    = hB + (long long)N_NODES * 128;
    float* pooled = agg + (long long)N_NODES * 64;

    const int BLK = 256;

    // ---- layer 1: 7 -> 8, input = x ----
    hipMemsetAsync(agg, 0, (size_t)N_NODES * 7 * sizeof(float), stream);
    edge_agg<3, 7><<<cdiv((long long)N_EDGES << 3, BLK), BLK, 0, stream>>>(x, src, dst, ea, agg);
    node_update<7, 8, 3><<<cdiv((long long)N_NODES * 8, BLK), BLK, 0, stream>>>(
        agg, x, w_rel[0], b_rel[0], w_root[0], hA);

    // ---- layer 2: 8 -> 16 ----
    hipMemsetAsync(agg, 0, (size_t)N_NODES * 8 * sizeof(float), stream);
    edge_agg<3, 8><<<cdiv((long long)N_EDGES << 3, BLK), BLK, 0, stream>>>(hA, src, dst, ea, agg);
    node_update<8, 16, 4><<<cdiv((long long)N_NODES * 16, BLK), BLK, 0, stream>>>(
        agg, hA, w_rel[1], b_rel[1], w_root[1], hB);

    // ---- layer 3: 16 -> 32 ----
    hipMemsetAsync(agg, 0, (size_t)N_NODES * 16 * sizeof(float), stream);
    edge_agg<4, 16><<<cdiv((long long)N_EDGES << 4, BLK), BLK, 0, stream>>>(hB, src, dst, ea, agg);
    node_update<16, 32, 5><<<cdiv((long long)N_NODES * 32, BLK), BLK, 0, stream>>>(
        agg, hB, w_rel[2], b_rel[2], w_root[2], hA);

    // ---- layer 4: 32 -> 64 ----
    hipMemsetAsync(agg, 0, (size_t)N_NODES * 32 * sizeof(float), stream);
    edge_agg<5, 32><<<cdiv((long long)N_EDGES << 5, BLK), BLK, 0, stream>>>(hA, src, dst, ea, agg);
    node_update<32, 64, 6><<<cdiv((long long)N_NODES * 64, BLK), BLK, 0, stream>>>(
        agg, hA, w_rel[3], b_rel[3], w_root[3], hB);

    // ---- layer 5: 64 -> 128 ----
    hipMemsetAsync(agg, 0, (size_t)N_NODES * 64 * sizeof(float), stream);
    edge_agg<6, 64><<<cdiv((long long)N_EDGES << 6, BLK), BLK, 0, stream>>>(hB, src, dst, ea, agg);
    node_update<64, 128, 7><<<cdiv((long long)N_NODES * 128, BLK), BLK, 0, stream>>>(
        agg, hB, w_rel[4], b_rel[4], w_root[4], hA);

    // ---- pooling + classifier ----
    hipMemsetAsync(pooled, 0, (size_t)N_GRAPHS * 128 * sizeof(float), stream);
    pool_kernel<<<cdiv(N_NODES, 256), 128, 0, stream>>>(hA, batch, pooled);
    final_kernel<<<1, 128, 0, stream>>>(pooled, w_lin, b_lin, out);
}

// Round 2
// 454.508 us; speedup vs baseline: 1.5621x; 1.5621x over previous
//
#include <hip/hip_runtime.h>

#define N_NODES 40000
#define N_EDGES 640000
#define N_GRAPHS 64

static inline int cdiv(long long a, int b) { return (int)((a + b - 1) / b); }

// ---------------------------- CSR build ------------------------------------
__global__ __launch_bounds__(256) void hist_kernel(const int* __restrict__ dst,
                                                   int* __restrict__ deg) {
    int e = blockIdx.x * 256 + threadIdx.x;
    if (e < N_EDGES) atomicAdd(&deg[dst[e]], 1);
}

__global__ __launch_bounds__(1024) void scan_kernel(const int* __restrict__ deg,
                                                    int* __restrict__ row_start,
                                                    int* __restrict__ cursor) {
    __shared__ int smem[1024];
    int tid = threadIdx.x;
    int base = 0;
    for (int chunk = 0; chunk < N_NODES; chunk += 1024) {
        int i = chunk + tid;
        int v = (i < N_NODES) ? deg[i] : 0;
        smem[tid] = v;
        __syncthreads();
        for (int off = 1; off < 1024; off <<= 1) {
            int t = (tid >= off) ? smem[tid - off] : 0;
            __syncthreads();
            smem[tid] += t;
            __syncthreads();
        }
        if (i < N_NODES) {
            int excl = base + smem[tid] - v;
            row_start[i] = excl;
            cursor[i] = excl;
        }
        base += smem[1023];
        __syncthreads();
    }
    if (tid == 0) row_start[N_NODES] = base;
}

__global__ __launch_bounds__(256) void scatter_kernel(const int* __restrict__ src,
                                                      const int* __restrict__ dst,
                                                      const float* __restrict__ ew,
                                                      int* __restrict__ cursor,
                                                      int* __restrict__ csr_src,
                                                      float* __restrict__ csr_w) {
    int e = blockIdx.x * 256 + threadIdx.x;
    if (e >= N_EDGES) return;
    int pos = atomicAdd(&cursor[dst[e]], 1);
    csr_src[pos] = src[e];
    csr_w[pos] = ew[e];
}

// ------------------- aggregation: agg[n] = sum_{e->n} w_e * x[src_e] -------
// scalar variant (FIN=7): (1<<LOGF) lanes per node, lane = feature
template<int FIN, int LOGF>
__global__ __launch_bounds__(256) void gather_scalar(const float* __restrict__ x,
                                                     const int* __restrict__ row_start,
                                                     const int* __restrict__ csr_src,
                                                     const float* __restrict__ csr_w,
                                                     float* __restrict__ agg) {
    long long tid = (long long)blockIdx.x * 256 + threadIdx.x;
    int n = (int)(tid >> LOGF);
    if (n >= N_NODES) return;
    int f = (int)(tid & ((1 << LOGF) - 1));
    int beg = row_start[n], end = row_start[n + 1];
    float acc = 0.f;
    for (int p = beg; p < end; ++p) {
        int s = csr_src[p];
        float w = csr_w[p];
        if (f < FIN) acc += w * x[(long long)s * FIN + f];
    }
    if (f < FIN) agg[(long long)n * FIN + f] = acc;
}

// vector variant (FIN%4==0): FIN/4 lanes per node, lane = float4 chunk
template<int FIN, int LOGF>  // 1<<LOGF == FIN/4
__global__ __launch_bounds__(256) void gather_vec(const float* __restrict__ x,
                                                  const int* __restrict__ row_start,
                                                  const int* __restrict__ csr_src,
                                                  const float* __restrict__ csr_w,
                                                  float* __restrict__ agg) {
    long long tid = (long long)blockIdx.x * 256 + threadIdx.x;
    int n = (int)(tid >> LOGF);
    if (n >= N_NODES) return;
    int f4 = (int)(tid & ((1 << LOGF) - 1));
    int beg = row_start[n], end = row_start[n + 1];
    float4 acc = {0.f, 0.f, 0.f, 0.f};
    for (int p = beg; p < end; ++p) {
        int s = csr_src[p];
        float w = csr_w[p];
        float4 v = *(const float4*)&x[(long long)s * FIN + f4 * 4];
        acc.x += w * v.x; acc.y += w * v.y; acc.z += w * v.z; acc.w += w * v.w;
    }
    *(float4*)&agg[(long long)n * FIN + f4 * 4] = acc;
}

// ------------------- node update: hout = agg@w_rel + b + hin@w_root --------
__device__ __forceinline__ void fma4(float4& a, float s, const float4& w) {
    a.x = fmaf(s, w.x, a.x);
    a.y = fmaf(s, w.y, a.y);
    a.z = fmaf(s, w.z, a.z);
    a.w = fmaf(s, w.w, a.w);
}

template<int FIN, int FOUT, int NT, bool FUSE_POOL, bool VEC>
__global__ __launch_bounds__(256) void node_update_t(const float* __restrict__ agg,
                                                     const float* __restrict__ hin,
                                                     const float* __restrict__ w_rel,
                                                     const float* __restrict__ b_rel,
                                                     const float* __restrict__ w_root,
                                                     float* __restrict__ hout,
                                                     const int* __restrict__ batch,
                                                     float* __restrict__ pooled) {
    constexpr int FG = FOUT / 4;        // float4 groups over fo
    constexpr int SLOTS = 256 / FG;     // node slots per block
    constexpr int BN = SLOTS * NT;      // nodes per block
    __shared__ float s_wrel[FIN * FOUT];
    __shared__ float s_wroot[FIN * FOUT];
    for (int i = threadIdx.x; i < FIN * FOUT; i += 256) {
        s_wrel[i] = w_rel[i];
        s_wroot[i] = w_root[i];
    }
    __syncthreads();
    int fg = threadIdx.x % FG;
    int slot = threadIdx.x / FG;
    int n0 = blockIdx.x * BN + slot * NT;
    float4 bias = *(const float4*)&b_rel[fg * 4];
    float4 acc[NT];
    #pragma unroll
    for (int t = 0; t < NT; ++t) acc[t] = bias;

    if constexpr (VEC) {
        #pragma unroll 4
        for (int c = 0; c < FIN / 4; ++c) {
            float4 wr[4], wo[4];
            #pragma unroll
            for (int k = 0; k < 4; ++k) {
                wr[k] = *(const float4*)&s_wrel[(c * 4 + k) * FOUT + fg * 4];
                wo[k] = *(const float4*)&s_wroot[(c * 4 + k) * FOUT + fg * 4];
            }
            #pragma unroll
            for (int t = 0; t < NT; ++t) {
                int n = n0 + t;
                if (n < N_NODES) {
                    float4 a = *(const float4*)&agg[(long long)n * FIN + c * 4];
                    float4 h = *(const float4*)&hin[(long long)n * FIN + c * 4];
                    fma4(acc[t], a.x, wr[0]); fma4(acc[t], a.y, wr[1]);
                    fma4(acc[t], a.z, wr[2]); fma4(acc[t], a.w, wr[3]);
                    fma4(acc[t], h.x, wo[0]); fma4(acc[t], h.y, wo[1]);
                    fma4(acc[t], h.z, wo[2]); fma4(acc[t], h.w, wo[3]);
                }
            }
        }
    } else {
        #pragma unroll
        for (int fi = 0; fi < FIN; ++fi) {
            float4 wr = *(const float4*)&s_wrel[fi * FOUT + fg * 4];
            float4 wo = *(const float4*)&s_wroot[fi * FOUT + fg * 4];
            #pragma unroll
            for (int t = 0; t < NT; ++t) {
                int n = n0 + t;
                if (n < N_NODES) {
                    float a = agg[(long long)n * FIN + fi];
                    float h = hin[(long long)n * FIN + fi];
                    fma4(acc[t], a, wr);
                    fma4(acc[t], h, wo);
                }
            }
        }
    }

    if constexpr (FUSE_POOL) {
        // batch is sorted: segmented accumulate, one atomic per segment change
        int gprev = -1;
        float4 ps = {0.f, 0.f, 0.f, 0.f};
        #pragma unroll
        for (int t = 0; t < NT; ++t) {
            int n = n0 + t;
            if (n < N_NODES) {
                int g = batch[n];
                if (g != gprev) {
                    if (gprev >= 0) {
                        float* p = &pooled[(long long)gprev * FOUT + fg * 4];
                        atomicAdd(p + 0, ps.x); atomicAdd(p + 1, ps.y);
                        atomicAdd(p + 2, ps.z); atomicAdd(p + 3, ps.w);
                        ps = {0.f, 0.f, 0.f, 0.f};
                    }
                    gprev = g;
                }
                ps.x += acc[t].x; ps.y += acc[t].y;
                ps.z += acc[t].z; ps.w += acc[t].w;
            }
        }
        if (gprev >= 0) {
            float* p = &pooled[(long long)gprev * FOUT + fg * 4];
            atomicAdd(p + 0, ps.x); atomicAdd(p + 1, ps.y);
            atomicAdd(p + 2, ps.z); atomicAdd(p + 3, ps.w);
        }
    } else {
        #pragma unroll
        for (int t = 0; t < NT; ++t) {
            int n = n0 + t;
            if (n < N_NODES) *(float4*)&hout[(long long)n * FOUT + fg * 4] = acc[t];
        }
    }
}

// ---------------- classifier: out = pooled @ w_lin + b_lin -----------------
__global__ void final_kernel(const float* __restrict__ pooled,
                             const float* __restrict__ w_lin,
                             const float* __restrict__ b_lin,
                             float* __restrict__ out) {
    int tid = threadIdx.x;  // 128 threads: (graph, class)
    int g = tid >> 1;
    int c = tid & 1;
    float acc = b_lin[c];
    #pragma unroll 8
    for (int fi = 0; fi < 128; ++fi)
        acc += pooled[g * 128 + fi] * w_lin[fi * 2 + c];
    out[g * 2 + c] = acc;
}

extern "C" void kernel_launch(void* const* d_in, const int* in_sizes, int n_in,
                              void* d_out, int out_size, void* d_ws, size_t ws_size,
                              hipStream_t stream) {
    const float* x     = (const float*)d_in[0];
    const int*   ei    = (const int*)d_in[1];
    const float* ea    = (const float*)d_in[2];
    const int*   batch = (const int*)d_in[3];
    const int* src = ei;
    const int* dst = ei + N_EDGES;

    const float* w_rel[5], *b_rel[5], *w_root[5];
    for (int i = 0; i < 5; ++i) {
        w_rel[i]  = (const float*)d_in[4 + 3 * i];
        b_rel[i]  = (const float*)d_in[5 + 3 * i];
        w_root[i] = (const float*)d_in[6 + 3 * i];
    }
    const float* w_lin = (const float*)d_in[19];
    const float* b_lin = (const float*)d_in[20];
    float* out = (float*)d_out;

    // workspace layout
    float* hA      = (float*)d_ws;                   // 40000*64
    float* hB      = hA + (long long)N_NODES * 64;   // 40000*64
    float* agg     = hB + (long long)N_NODES * 64;   // 40000*64
    float* pooled  = agg + (long long)N_NODES * 64;  // 64*128
    float* csr_w   = pooled + N_GRAPHS * 128;        // 640000
    int* csr_src   = (int*)(csr_w + N_EDGES);        // 640000
    int* deg       = csr_src + N_EDGES;              // 40000
    int* row_start = deg + N_NODES;                  // 40001
    int* cursor    = row_start + N_NODES + 1;        // 40000

    const int BLK = 256;
    const int EB = cdiv(N_EDGES, BLK);

    // ---- CSR build (atomic-free aggregation afterwards) ----
    hipMemsetAsync(deg, 0, (size_t)N_NODES * sizeof(int), stream);
    hist_kernel<<<EB, BLK, 0, stream>>>(dst, deg);
    scan_kernel<<<1, 1024, 0, stream>>>(deg, row_start, cursor);
    scatter_kernel<<<EB, BLK, 0, stream>>>(src, dst, ea, cursor, csr_src, csr_w);

    // ---- layer 1: 7 -> 8 ----
    gather_scalar<7, 3><<<cdiv((long long)N_NODES << 3, BLK), BLK, 0, stream>>>(
        x, row_start, csr_src, csr_w, agg);
    node_update_t<7, 8, 2, false, false><<<cdiv(N_NODES, 256), BLK, 0, stream>>>(
        agg, x, w_rel[0], b_rel[0], w_root[0], hA, nullptr, nullptr);

    // ---- layer 2: 8 -> 16 ----
    gather_vec<8, 1><<<cdiv((long long)N_NODES << 1, BLK), BLK, 0, stream>>>(
        hA, row_start, csr_src, csr_w, agg);
    node_update_t<8, 16, 2, false, true><<<cdiv(N_NODES, 128), BLK, 0, stream>>>(
        agg, hA, w_rel[1], b_rel[1], w_root[1], hB, nullptr, nullptr);

    // ---- layer 3: 16 -> 32 ----
    gather_vec<16, 2><<<cdiv((long long)N_NODES << 2, BLK), BLK, 0, stream>>>(
        hB, row_start, csr_src, csr_w, agg);
    node_update_t<16, 32, 2, false, true><<<cdiv(N_NODES, 64), BLK, 0, stream>>>(
        agg, hB, w_rel[2], b_rel[2], w_root[2], hA, nullptr, nullptr);

    // ---- layer 4: 32 -> 64 ----
    gather_vec<32, 3><<<cdiv((long long)N_NODES << 3, BLK), BLK, 0, stream>>>(
        hA, row_start, csr_src, csr_w, agg);
    node_update_t<32, 64, 4, false, true><<<cdiv(N_NODES, 64), BLK, 0, stream>>>(
        agg, hA, w_rel[3], b_rel[3], w_root[3], hB, nullptr, nullptr);

    // ---- layer 5: 64 -> 128, pooling fused ----
    gather_vec<64, 4><<<cdiv((long long)N_NODES << 4, BLK), BLK, 0, stream>>>(
        hB, row_start, csr_src, csr_w, agg);
    hipMemsetAsync(pooled, 0, (size_t)N_GRAPHS * 128 * sizeof(float), stream);
    node_update_t<64, 128, 4, true, true><<<cdiv(N_NODES, 32), BLK, 0, stream>>>(
        agg, hB, w_rel[4], b_rel[4], w_root[4], nullptr, batch, pooled);

    // ---- classifier ----
    final_kernel<<<1, 128, 0, stream>>>(pooled, w_lin, b_lin, out);
}

// Round 3
// 381.339 us; speedup vs baseline: 1.8618x; 1.1919x over previous
//
#include <hip/hip_runtime.h>

#define N_NODES 40000
#define N_EDGES 640000
#define N_GRAPHS 64

typedef unsigned short u16;
typedef unsigned int u32;

static inline int cdiv(long long a, int b) { return (int)((a + b - 1) / b); }

// ---------------- bf16 helpers (OCP bf16 = top 16 bits of fp32) ------------
__device__ __forceinline__ u16 f2bf(float f) {
    u32 u = __float_as_uint(f);
    u32 r = (u + 0x7fffu + ((u >> 16) & 1u)) >> 16;  // round-to-nearest-even
    return (u16)r;
}
__device__ __forceinline__ u32 packpair(float a, float b) {
    return (u32)f2bf(a) | ((u32)f2bf(b) << 16);
}
__device__ __forceinline__ void unpack8(uint4 q, float* o) {
    o[0] = __uint_as_float(q.x << 16); o[1] = __uint_as_float(q.x & 0xffff0000u);
    o[2] = __uint_as_float(q.y << 16); o[3] = __uint_as_float(q.y & 0xffff0000u);
    o[4] = __uint_as_float(q.z << 16); o[5] = __uint_as_float(q.z & 0xffff0000u);
    o[6] = __uint_as_float(q.w << 16); o[7] = __uint_as_float(q.w & 0xffff0000u);
}

__device__ __forceinline__ void fma4(float4& a, float s, const float4& w) {
    a.x = fmaf(s, w.x, a.x);
    a.y = fmaf(s, w.y, a.y);
    a.z = fmaf(s, w.z, a.z);
    a.w = fmaf(s, w.w, a.w);
}

// ---------------------------- CSR build ------------------------------------
__global__ __launch_bounds__(256) void hist_kernel(const int* __restrict__ dst,
                                                   int* __restrict__ deg) {
    int e = blockIdx.x * 256 + threadIdx.x;
    if (e < N_EDGES) atomicAdd(&deg[dst[e]], 1);
}

// single block, 1024 threads, each scans 40 contiguous nodes; shfl+LDS scan
__global__ __launch_bounds__(1024) void scan_kernel(const int* __restrict__ deg,
                                                    int* __restrict__ row_start,
                                                    int* __restrict__ cursor) {
    const int PER = 40;  // 1024*40 = 40960 >= N_NODES+1
    __shared__ int wtot[16];
    __shared__ int woff[16];
    int t = threadIdx.x;
    int base = t * PER;
    int loc[PER];
    int sum = 0;
    #pragma unroll
    for (int i = 0; i < PER; ++i) {
        int idx = base + i;
        int v = (idx < N_NODES) ? deg[idx] : 0;
        loc[i] = sum;
        sum += v;
    }
    int lane = t & 63, wid = t >> 6;
    int inc = sum;
    for (int off = 1; off < 64; off <<= 1) {
        int y = __shfl_up(inc, off, 64);
        if (lane >= off) inc += y;
    }
    if (lane == 63) wtot[wid] = inc;
    __syncthreads();
    if (t == 0) {
        int r = 0;
        for (int i = 0; i < 16; ++i) { woff[i] = r; r += wtot[i]; }
    }
    __syncthreads();
    int excl = woff[wid] + inc - sum;  // exclusive prefix of per-thread sums
    #pragma unroll
    for (int i = 0; i < PER; ++i) {
        int idx = base + i;
        if (idx < N_NODES) {
            int v = excl + loc[i];
            row_start[idx] = v;
            cursor[idx] = v;
        } else if (idx == N_NODES) {
            row_start[idx] = excl + loc[i];
        }
    }
}

__global__ __launch_bounds__(256) void scatter_kernel(const int* __restrict__ src,
                                                      const int* __restrict__ dst,
                                                      const float* __restrict__ ew,
                                                      int* __restrict__ cursor,
                                                      int* __restrict__ csr_src,
                                                      float* __restrict__ csr_w) {
    int e = blockIdx.x * 256 + threadIdx.x;
    if (e >= N_EDGES) return;
    int pos = atomicAdd(&cursor[dst[e]], 1);
    csr_src[pos] = src[e];
    csr_w[pos] = ew[e];
}

// ---------------- layer-1 gather: fp32 x (FIN=7) ---------------------------
// 16 lanes per node: 8 feature lanes x 2 edge-halves; shfl_xor(8) combine.
__global__ __launch_bounds__(256) void gather1(const float* __restrict__ x,
                                               const int* __restrict__ rs,
                                               const int* __restrict__ csrc,
                                               const float* __restrict__ cw,
                                               float* __restrict__ agg) {
    long long tid = (long long)blockIdx.x * 256 + threadIdx.x;
    int n = (int)(tid >> 4);
    if (n >= N_NODES) return;
    int sub = (int)(tid & 15);
    int f = sub & 7;
    int half = sub >> 3;
    int beg = rs[n], end = rs[n + 1];
    float acc = 0.f;
    int p = beg + half;
    int s = 0; float w = 0.f;
    if (p < end) { s = csrc[p]; w = cw[p]; }
    while (p < end) {
        float v = (f < 7) ? x[(long long)s * 7 + f] : 0.f;
        float wc = w;
        int pn = p + 2;
        if (pn < end) { s = csrc[pn]; w = cw[pn]; }
        acc = fmaf(wc, v, acc);
        p = pn;
    }
    acc += __shfl_xor(acc, 8, 64);
    if (half == 0 && f < 7) agg[(long long)n * 7 + f] = acc;
}

// ---------------- bf16 gather: FIN = 8<<LOGF -------------------------------
// (2<<LOGF) lanes/node: (1<<LOGF) 8-feature chunks x 2 edge-halves.
template<int LOGF, int IN_STRIDE, int IN_OFF, int OUT_STRIDE, int OUT_OFF>
__global__ __launch_bounds__(256) void gather_bf16(const u16* __restrict__ hbuf,
                                                   const int* __restrict__ rs,
                                                   const int* __restrict__ csrc,
                                                   const float* __restrict__ cw,
                                                   u16* __restrict__ obuf) {
    long long tid = (long long)blockIdx.x * 256 + threadIdx.x;
    int n = (int)(tid >> (LOGF + 1));
    if (n >= N_NODES) return;
    int sub = (int)(tid & ((2 << LOGF) - 1));
    int c = sub & ((1 << LOGF) - 1);
    int half = sub >> LOGF;
    const u16* base = hbuf + IN_OFF + c * 8;
    int beg = rs[n], end = rs[n + 1];
    float acc[8] = {0.f, 0.f, 0.f, 0.f, 0.f, 0.f, 0.f, 0.f};
    int p = beg + half;
    int s = 0; float w = 0.f;
    if (p < end) { s = csrc[p]; w = cw[p]; }
    while (p < end) {
        uint4 q = *(const uint4*)(base + (long long)s * IN_STRIDE);
        float wc = w;
        int pn = p + 2;
        if (pn < end) { s = csrc[pn]; w = cw[pn]; }
        float tv[8];
        unpack8(q, tv);
        #pragma unroll
        for (int j = 0; j < 8; ++j) acc[j] = fmaf(wc, tv[j], acc[j]);
        p = pn;
    }
    #pragma unroll
    for (int j = 0; j < 8; ++j) acc[j] += __shfl_xor(acc[j], 1 << LOGF, 64);
    if (half == 0) {
        uint4 o;
        o.x = packpair(acc[0], acc[1]); o.y = packpair(acc[2], acc[3]);
        o.z = packpair(acc[4], acc[5]); o.w = packpair(acc[6], acc[7]);
        *(uint4*)(obuf + (long long)n * OUT_STRIDE + OUT_OFF + c * 8) = o;
    }
}

// ---------------- layer-1 node update (fp32 in, bf16 out) ------------------
__global__ __launch_bounds__(256) void node1(const float* __restrict__ agg,
                                             const float* __restrict__ x,
                                             const float* __restrict__ wr,
                                             const float* __restrict__ br,
                                             const float* __restrict__ wo,
                                             u16* __restrict__ obuf) {
    __shared__ float swr[56], swo[56], sb[8];
    if (threadIdx.x < 56) { swr[threadIdx.x] = wr[threadIdx.x]; swo[threadIdx.x] = wo[threadIdx.x]; }
    if (threadIdx.x < 8) sb[threadIdx.x] = br[threadIdx.x];
    __syncthreads();
    int n = blockIdx.x * 256 + threadIdx.x;
    if (n >= N_NODES) return;
    float a[7], h[7];
    #pragma unroll
    for (int i = 0; i < 7; ++i) {
        a[i] = agg[(long long)n * 7 + i];
        h[i] = x[(long long)n * 7 + i];
    }
    float o[8];
    #pragma unroll
    for (int j = 0; j < 8; ++j) {
        float s = sb[j];
        #pragma unroll
        for (int i = 0; i < 7; ++i) s = fmaf(a[i], swr[i * 8 + j], fmaf(h[i], swo[i * 8 + j], s));
        o[j] = s;
    }
    uint4 q;
    q.x = packpair(o[0], o[1]); q.y = packpair(o[2], o[3]);
    q.z = packpair(o[4], o[5]); q.w = packpair(o[6], o[7]);
    *(uint4*)(obuf + (long long)n * 16 + 8) = q;  // hin half of buf2
}

// ---------------- generic node update: A[K bf16 rows] @ [wrel;wroot] -------
template<int K, int FOUT, int FO_TILE, int NT, int OUT_STRIDE, int OUT_OFF, bool POOL>
__global__ __launch_bounds__(256) void node_mm(const u16* __restrict__ abuf,
                                               const float* __restrict__ w_rel,
                                               const float* __restrict__ b_rel,
                                               const float* __restrict__ w_root,
                                               u16* __restrict__ obuf,
                                               const int* __restrict__ batch,
                                               float* __restrict__ pooled) {
    constexpr int FG = FO_TILE / 4;
    constexpr int SLOTS = 256 / FG;
    constexpr int BN = SLOTS * NT;
    __shared__ float sw[K][FO_TILE];
    int fo0 = blockIdx.y * FO_TILE;
    for (int i = threadIdx.x; i < K * FO_TILE; i += 256) {
        int k = i / FO_TILE, j = i % FO_TILE;
        sw[k][j] = (k < K / 2) ? w_rel[k * FOUT + fo0 + j]
                               : w_root[(k - K / 2) * FOUT + fo0 + j];
    }
    __syncthreads();
    int fg = threadIdx.x % FG;
    int slot = threadIdx.x / FG;
    int n0 = blockIdx.x * BN + slot * NT;
    float4 bias = *(const float4*)&b_rel[fo0 + fg * 4];
    float4 acc[NT];
    #pragma unroll
    for (int t = 0; t < NT; ++t) acc[t] = bias;

    #pragma unroll
    for (int kc = 0; kc < K / 8; ++kc) {
        float4 wv[8];
        #pragma unroll
        for (int k = 0; k < 8; ++k) wv[k] = *(const float4*)&sw[kc * 8 + k][fg * 4];
        #pragma unroll
        for (int t = 0; t < NT; ++t) {
            int n = n0 + t;
            if (n < N_NODES) {
                uint4 q = *(const uint4*)(abuf + (long long)n * K + kc * 8);
                float av[8];
                unpack8(q, av);
                #pragma unroll
                for (int k = 0; k < 8; ++k) fma4(acc[t], av[k], wv[k]);
            }
        }
    }

    if constexpr (!POOL) {
        #pragma unroll
        for (int t = 0; t < NT; ++t) {
            int n = n0 + t;
            if (n < N_NODES) {
                uint2 o;
                o.x = packpair(acc[t].x, acc[t].y);
                o.y = packpair(acc[t].z, acc[t].w);
                *(uint2*)(obuf + (long long)n * OUT_STRIDE + OUT_OFF + fo0 + fg * 4) = o;
            }
        }
    } else {
        int gprev = -1;
        float4 ps = {0.f, 0.f, 0.f, 0.f};
        #pragma unroll
        for (int t = 0; t < NT; ++t) {
            int n = n0 + t;
            if (n < N_NODES) {
                int g = batch[n];
                if (g != gprev) {
                    if (gprev >= 0) {
                        float* pp = &pooled[gprev * FOUT + fo0 + fg * 4];
                        atomicAdd(pp + 0, ps.x); atomicAdd(pp + 1, ps.y);
                        atomicAdd(pp + 2, ps.z); atomicAdd(pp + 3, ps.w);
                        ps = {0.f, 0.f, 0.f, 0.f};
                    }
                    gprev = g;
                }
                ps.x += acc[t].x; ps.y += acc[t].y;
                ps.z += acc[t].z; ps.w += acc[t].w;
            }
        }
        if (gprev >= 0) {
            float* pp = &pooled[gprev * FOUT + fo0 + fg * 4];
            atomicAdd(pp + 0, ps.x); atomicAdd(pp + 1, ps.y);
            atomicAdd(pp + 2, ps.z); atomicAdd(pp + 3, ps.w);
        }
    }
}

// ---------------- classifier -----------------------------------------------
__global__ void final_kernel(const float* __restrict__ pooled,
                             const float* __restrict__ w_lin,
                             const float* __restrict__ b_lin,
                             float* __restrict__ out) {
    int tid = threadIdx.x;
    int g = tid >> 1;
    int c = tid & 1;
    float acc = b_lin[c];
    #pragma unroll 8
    for (int fi = 0; fi < 128; ++fi)
        acc += pooled[g * 128 + fi] * w_lin[fi * 2 + c];
    out[g * 2 + c] = acc;
}

extern "C" void kernel_launch(void* const* d_in, const int* in_sizes, int n_in,
                              void* d_out, int out_size, void* d_ws, size_t ws_size,
                              hipStream_t stream) {
    const float* x     = (const float*)d_in[0];
    const int*   ei    = (const int*)d_in[1];
    const float* ea    = (const float*)d_in[2];
    const int*   batch = (const int*)d_in[3];
    const int* src = ei;
    const int* dst = ei + N_EDGES;

    const float* w_rel[5], *b_rel[5], *w_root[5];
    for (int i = 0; i < 5; ++i) {
        w_rel[i]  = (const float*)d_in[4 + 3 * i];
        b_rel[i]  = (const float*)d_in[5 + 3 * i];
        w_root[i] = (const float*)d_in[6 + 3 * i];
    }
    const float* w_lin = (const float*)d_in[19];
    const float* b_lin = (const float*)d_in[20];
    float* out = (float*)d_out;

    // ---- workspace layout (16B-aligned sections) ----
    float* agg1   = (float*)d_ws;                      // 40000*7 fp32
    u16*   buf2   = (u16*)(agg1 + 280000);             // 40000*16 bf16 [agg|hin]
    u16*   buf3   = buf2 + 640000;                     // 40000*32
    u16*   buf4   = buf3 + 1280000;                    // 40000*64
    u16*   buf5   = buf4 + 2560000;                    // 40000*128
    float* pooled = (float*)(buf5 + 5120000);          // 64*128 fp32
    float* csr_w  = pooled + N_GRAPHS * 128;           // 640000
    int* csr_src  = (int*)(csr_w + N_EDGES);           // 640000
    int* deg      = csr_src + N_EDGES;                 // 40000
    int* rs       = deg + N_NODES;                     // 40001
    int* cursor   = rs + N_NODES + 1;                  // 40000

    const int BLK = 256;
    const int EB = cdiv(N_EDGES, BLK);

    // ---- CSR build ----
    hipMemsetAsync(deg, 0, (size_t)N_NODES * sizeof(int), stream);
    hist_kernel<<<EB, BLK, 0, stream>>>(dst, deg);
    scan_kernel<<<1, 1024, 0, stream>>>(deg, rs, cursor);
    scatter_kernel<<<EB, BLK, 0, stream>>>(src, dst, ea, cursor, csr_src, csr_w);

    // ---- layer 1: 7 -> 8 (fp32 in, bf16 out into buf2.hin) ----
    gather1<<<cdiv((long long)N_NODES * 16, BLK), BLK, 0, stream>>>(x, rs, csr_src, csr_w, agg1);
    node1<<<cdiv(N_NODES, 256), BLK, 0, stream>>>(agg1, x, w_rel[0], b_rel[0], w_root[0], buf2);

    // ---- layer 2: 8 -> 16 ----
    gather_bf16<0, 16, 8, 16, 0><<<cdiv((long long)N_NODES * 2, BLK), BLK, 0, stream>>>(
        buf2, rs, csr_src, csr_w, buf2);
    node_mm<16, 16, 16, 4, 32, 16, false><<<dim3(cdiv(N_NODES, 256), 1), BLK, 0, stream>>>(
        buf2, w_rel[1], b_rel[1], w_root[1], buf3, nullptr, nullptr);

    // ---- layer 3: 16 -> 32 ----
    gather_bf16<1, 32, 16, 32, 0><<<cdiv((long long)N_NODES * 4, BLK), BLK, 0, stream>>>(
        buf3, rs, csr_src, csr_w, buf3);
    node_mm<32, 32, 32, 4, 64, 32, false><<<dim3(cdiv(N_NODES, 128), 1), BLK, 0, stream>>>(
        buf3, w_rel[2], b_rel[2], w_root[2], buf4, nullptr, nullptr);

    // ---- layer 4: 32 -> 64 ----
    gather_bf16<2, 64, 32, 64, 0><<<cdiv((long long)N_NODES * 8, BLK), BLK, 0, stream>>>(
        buf4, rs, csr_src, csr_w, buf4);
    node_mm<64, 64, 64, 8, 128, 64, false><<<dim3(cdiv(N_NODES, 128), 1), BLK, 0, stream>>>(
        buf4, w_rel[3], b_rel[3], w_root[3], buf5, nullptr, nullptr);

    // ---- layer 5: 64 -> 128, pooling fused ----
    gather_bf16<3, 128, 64, 128, 0><<<cdiv((long long)N_NODES * 16, BLK), BLK, 0, stream>>>(
        buf5, rs, csr_src, csr_w, buf5);
    hipMemsetAsync(pooled, 0, (size_t)N_GRAPHS * 128 * sizeof(float), stream);
    node_mm<128, 128, 64, 8, 0, 0, true><<<dim3(cdiv(N_NODES, 128), 2), BLK, 0, stream>>>(
        buf5, w_rel[4], b_rel[4], w_root[4], nullptr, batch, pooled);

    // ---- classifier ----
    final_kernel<<<1, 128, 0, stream>>>(pooled, w_lin, b_lin, out);
}

// Round 4
// 316.985 us; speedup vs baseline: 2.2398x; 1.2030x over previous
//
#include <hip/hip_runtime.h>

#define N_NODES 40000
#define N_EDGES 640000
#define N_GRAPHS 64

typedef unsigned short u16;
typedef unsigned int u32;

static inline int cdiv(long long a, int b) { return (int)((a + b - 1) / b); }

// ---------------- bf16 helpers (bf16 = top 16 bits of fp32) ----------------
__device__ __forceinline__ u16 f2bf(float f) {
    u32 u = __float_as_uint(f);
    u32 r = (u + 0x7fffu + ((u >> 16) & 1u)) >> 16;  // round-to-nearest-even
    return (u16)r;
}
__device__ __forceinline__ u32 packpair(float a, float b) {
    return (u32)f2bf(a) | ((u32)f2bf(b) << 16);
}
__device__ __forceinline__ void unpack8(uint4 q, float* o) {
    o[0] = __uint_as_float(q.x << 16); o[1] = __uint_as_float(q.x & 0xffff0000u);
    o[2] = __uint_as_float(q.y << 16); o[3] = __uint_as_float(q.y & 0xffff0000u);
    o[4] = __uint_as_float(q.z << 16); o[5] = __uint_as_float(q.z & 0xffff0000u);
    o[6] = __uint_as_float(q.w << 16); o[7] = __uint_as_float(q.w & 0xffff0000u);
}
__device__ __forceinline__ void fma4(float4& a, float s, const float4& w) {
    a.x = fmaf(s, w.x, a.x);
    a.y = fmaf(s, w.y, a.y);
    a.z = fmaf(s, w.z, a.z);
    a.w = fmaf(s, w.w, a.w);
}

// ---------------------------- CSR build ------------------------------------
__global__ __launch_bounds__(256) void hist_kernel(const int* __restrict__ dst,
                                                   int* __restrict__ deg) {
    int e = blockIdx.x * 256 + threadIdx.x;
    if (e < N_EDGES) atomicAdd(&deg[dst[e]], 1);
}

// Phase 1: per-block (1024-wide) exclusive scan, block sums to bsum. grid=40.
__global__ __launch_bounds__(1024) void scan_part(const int* __restrict__ deg,
                                                  int* __restrict__ row_start,
                                                  int* __restrict__ bsum) {
    __shared__ int wtot[16], woff[16];
    int tid = threadIdx.x;
    int i = blockIdx.x * 1024 + tid;
    int v = (i < N_NODES) ? deg[i] : 0;
    int lane = tid & 63, wid = tid >> 6;
    int inc = v;
    #pragma unroll
    for (int off = 1; off < 64; off <<= 1) {
        int y = __shfl_up(inc, off, 64);
        if (lane >= off) inc += y;
    }
    if (lane == 63) wtot[wid] = inc;
    __syncthreads();
    if (tid < 16) {
        int b = wtot[tid];
        #pragma unroll
        for (int off = 1; off < 16; off <<= 1) {
            int y = __shfl_up(b, off, 16);
            if ((tid & 15) >= off) b += y;
        }
        woff[tid] = b - wtot[tid];
        if (tid == 15) bsum[blockIdx.x] = b;
    }
    __syncthreads();
    if (i <= N_NODES) row_start[i] = woff[wid] + inc - v;  // local exclusive
}

// Phase 2: add prefix of block sums; fill cursor. grid=40.
__global__ __launch_bounds__(1024) void scan_add(int* __restrict__ row_start,
                                                 const int* __restrict__ bsum,
                                                 int* __restrict__ cursor) {
    __shared__ int sbase;
    int tid = threadIdx.x;
    if (tid < 64) {
        int b = (tid < blockIdx.x) ? bsum[tid] : 0;
        #pragma unroll
        for (int off = 32; off; off >>= 1) b += __shfl_xor(b, off, 64);
        if (tid == 0) sbase = b;
    }
    __syncthreads();
    int i = blockIdx.x * 1024 + tid;
    if (i <= N_NODES) {
        int v = row_start[i] + sbase;
        row_start[i] = v;
        if (i < N_NODES) cursor[i] = v;
    }
}

__global__ __launch_bounds__(256) void scatter_kernel(const int* __restrict__ src,
                                                      const int* __restrict__ dst,
                                                      const float* __restrict__ ew,
                                                      int* __restrict__ cursor,
                                                      int2* __restrict__ csr_pair) {
    int e = blockIdx.x * 256 + threadIdx.x;
    if (e >= N_EDGES) return;
    int pos = atomicAdd(&cursor[dst[e]], 1);
    int2 q;
    q.x = src[e];
    q.y = __float_as_int(ew[e]);
    csr_pair[pos] = q;
}

// ---------------- layer-1 gather: fp32 x (FIN=7), 8*(1<<SLOG) lanes/node ---
template<int SLOG>
__global__ __launch_bounds__(256) void gather1(const float* __restrict__ x,
                                               const int* __restrict__ rs,
                                               const int2* __restrict__ pair,
                                               float* __restrict__ agg) {
    const int S = 1 << SLOG;
    long long tid = (long long)blockIdx.x * 256 + threadIdx.x;
    int n = (int)(tid >> (3 + SLOG));
    if (n >= N_NODES) return;
    int sub = (int)(tid & ((8 << SLOG) - 1));
    int f = sub & 7;
    int half = sub >> 3;
    int beg = rs[n], end = rs[n + 1];
    float acc = 0.f;
    int p = beg + half;
    int s = 0; float w = 0.f;
    if (p < end) { int2 q = pair[p]; s = q.x; w = __int_as_float(q.y); }
    while (p < end) {
        float v = (f < 7) ? x[(long long)s * 7 + f] : 0.f;
        float wc = w;
        int pn = p + S;
        if (pn < end) { int2 q = pair[pn]; s = q.x; w = __int_as_float(q.y); }
        acc = fmaf(wc, v, acc);
        p = pn;
    }
    #pragma unroll
    for (int d = 8; d < (8 << SLOG); d <<= 1) acc += __shfl_xor(acc, d, 64);
    if (half == 0 && f < 7) agg[(long long)n * 7 + f] = acc;
}

// ---------------- bf16 gather: FIN = 8<<LOGF, (1<<(LOGF+SLOG)) lanes/node --
template<int LOGF, int SLOG, int IN_STRIDE, int IN_OFF, int OUT_STRIDE, int OUT_OFF>
__global__ __launch_bounds__(256) void gather_bf16(const u16* __restrict__ hbuf,
                                                   const int* __restrict__ rs,
                                                   const int2* __restrict__ pair,
                                                   u16* __restrict__ obuf) {
    const int S = 1 << SLOG;
    long long tid = (long long)blockIdx.x * 256 + threadIdx.x;
    int n = (int)(tid >> (LOGF + SLOG));
    if (n >= N_NODES) return;
    int sub = (int)(tid & ((1 << (LOGF + SLOG)) - 1));
    int c = sub & ((1 << LOGF) - 1);
    int half = sub >> LOGF;
    const u16* base = hbuf + IN_OFF + c * 8;
    int beg = rs[n], end = rs[n + 1];
    float acc[8] = {0.f, 0.f, 0.f, 0.f, 0.f, 0.f, 0.f, 0.f};
    int p = beg + half;
    int s = 0; float w = 0.f;
    if (p < end) { int2 q = pair[p]; s = q.x; w = __int_as_float(q.y); }
    while (p < end) {
        uint4 rq = *(const uint4*)(base + (long long)s * IN_STRIDE);
        float wc = w;
        int pn = p + S;
        if (pn < end) { int2 q = pair[pn]; s = q.x; w = __int_as_float(q.y); }
        float tv[8];
        unpack8(rq, tv);
        #pragma unroll
        for (int j = 0; j < 8; ++j) acc[j] = fmaf(wc, tv[j], acc[j]);
        p = pn;
    }
    #pragma unroll
    for (int d = (1 << LOGF); d < (1 << (LOGF + SLOG)); d <<= 1) {
        #pragma unroll
        for (int j = 0; j < 8; ++j) acc[j] += __shfl_xor(acc[j], d, 64);
    }
    if (half == 0) {
        uint4 o;
        o.x = packpair(acc[0], acc[1]); o.y = packpair(acc[2], acc[3]);
        o.z = packpair(acc[4], acc[5]); o.w = packpair(acc[6], acc[7]);
        *(uint4*)(obuf + (long long)n * OUT_STRIDE + OUT_OFF + c * 8) = o;
    }
}

// ---------------- layer-1 node update (fp32 in, bf16 out) ------------------
__global__ __launch_bounds__(256) void node1(const float* __restrict__ agg,
                                             const float* __restrict__ x,
                                             const float* __restrict__ wr,
                                             const float* __restrict__ br,
                                             const float* __restrict__ wo,
                                             u16* __restrict__ obuf) {
    __shared__ float swr[56], swo[56], sb[8];
    if (threadIdx.x < 56) { swr[threadIdx.x] = wr[threadIdx.x]; swo[threadIdx.x] = wo[threadIdx.x]; }
    if (threadIdx.x < 8) sb[threadIdx.x] = br[threadIdx.x];
    __syncthreads();
    int n = blockIdx.x * 256 + threadIdx.x;
    if (n >= N_NODES) return;
    float a[7], h[7];
    #pragma unroll
    for (int i = 0; i < 7; ++i) {
        a[i] = agg[(long long)n * 7 + i];
        h[i] = x[(long long)n * 7 + i];
    }
    float o[8];
    #pragma unroll
    for (int j = 0; j < 8; ++j) {
        float s = sb[j];
        #pragma unroll
        for (int i = 0; i < 7; ++i) s = fmaf(a[i], swr[i * 8 + j], fmaf(h[i], swo[i * 8 + j], s));
        o[j] = s;
    }
    uint4 q;
    q.x = packpair(o[0], o[1]); q.y = packpair(o[2], o[3]);
    q.z = packpair(o[4], o[5]); q.w = packpair(o[6], o[7]);
    *(uint4*)(obuf + (long long)n * 16 + 8) = q;  // hin half of buf2
}

// ---------------- generic node update: A[K bf16] @ [wrel;wroot] ------------
template<int K, int FOUT, int FO_TILE, int NT, int OUT_STRIDE, int OUT_OFF, bool POOL>
__global__ __launch_bounds__(256) void node_mm(const u16* __restrict__ abuf,
                                               const float* __restrict__ w_rel,
                                               const float* __restrict__ b_rel,
                                               const float* __restrict__ w_root,
                                               u16* __restrict__ obuf,
                                               const int* __restrict__ batch,
                                               float* __restrict__ pooled) {
    constexpr int FG = FO_TILE / 4;
    constexpr int SLOTS = 256 / FG;
    constexpr int BN = SLOTS * NT;
    __shared__ float sw[K][FO_TILE];
    int fo0 = blockIdx.y * FO_TILE;
    for (int i = threadIdx.x; i < K * FO_TILE; i += 256) {
        int k = i / FO_TILE, j = i % FO_TILE;
        sw[k][j] = (k < K / 2) ? w_rel[k * FOUT + fo0 + j]
                               : w_root[(k - K / 2) * FOUT + fo0 + j];
    }
    __syncthreads();
    int fg = threadIdx.x % FG;
    int slot = threadIdx.x / FG;
    int n0 = blockIdx.x * BN + slot * NT;
    float4 bias = *(const float4*)&b_rel[fo0 + fg * 4];
    float4 acc[NT];
    #pragma unroll
    for (int t = 0; t < NT; ++t) acc[t] = bias;

    #pragma unroll
    for (int kc = 0; kc < K / 8; ++kc) {
        float4 wv[8];
        #pragma unroll
        for (int k = 0; k < 8; ++k) wv[k] = *(const float4*)&sw[kc * 8 + k][fg * 4];
        #pragma unroll
        for (int t = 0; t < NT; ++t) {
            int n = n0 + t;
            if (n < N_NODES) {
                uint4 q = *(const uint4*)(abuf + (long long)n * K + kc * 8);
                float av[8];
                unpack8(q, av);
                #pragma unroll
                for (int k = 0; k < 8; ++k) fma4(acc[t], av[k], wv[k]);
            }
        }
    }

    if constexpr (!POOL) {
        #pragma unroll
        for (int t = 0; t < NT; ++t) {
            int n = n0 + t;
            if (n < N_NODES) {
                uint2 o;
                o.x = packpair(acc[t].x, acc[t].y);
                o.y = packpair(acc[t].z, acc[t].w);
                *(uint2*)(obuf + (long long)n * OUT_STRIDE + OUT_OFF + fo0 + fg * 4) = o;
            }
        }
    } else {
        int gprev = -1;
        float4 ps = {0.f, 0.f, 0.f, 0.f};
        #pragma unroll
        for (int t = 0; t < NT; ++t) {
            int n = n0 + t;
            if (n < N_NODES) {
                int g = batch[n];
                if (g != gprev) {
                    if (gprev >= 0) {
                        float* pp = &pooled[gprev * FOUT + fo0 + fg * 4];
                        atomicAdd(pp + 0, ps.x); atomicAdd(pp + 1, ps.y);
                        atomicAdd(pp + 2, ps.z); atomicAdd(pp + 3, ps.w);
                        ps = {0.f, 0.f, 0.f, 0.f};
                    }
                    gprev = g;
                }
                ps.x += acc[t].x; ps.y += acc[t].y;
                ps.z += acc[t].z; ps.w += acc[t].w;
            }
        }
        if (gprev >= 0) {
            float* pp = &pooled[gprev * FOUT + fo0 + fg * 4];
            atomicAdd(pp + 0, ps.x); atomicAdd(pp + 1, ps.y);
            atomicAdd(pp + 2, ps.z); atomicAdd(pp + 3, ps.w);
        }
    }
}

// ---------------- classifier -----------------------------------------------
__global__ void final_kernel(const float* __restrict__ pooled,
                             const float* __restrict__ w_lin,
                             const float* __restrict__ b_lin,
                             float* __restrict__ out) {
    int tid = threadIdx.x;
    int g = tid >> 1;
    int c = tid & 1;
    float acc = b_lin[c];
    #pragma unroll 8
    for (int fi = 0; fi < 128; ++fi)
        acc += pooled[g * 128 + fi] * w_lin[fi * 2 + c];
    out[g * 2 + c] = acc;
}

extern "C" void kernel_launch(void* const* d_in, const int* in_sizes, int n_in,
                              void* d_out, int out_size, void* d_ws, size_t ws_size,
                              hipStream_t stream) {
    const float* x     = (const float*)d_in[0];
    const int*   ei    = (const int*)d_in[1];
    const float* ea    = (const float*)d_in[2];
    const int*   batch = (const int*)d_in[3];
    const int* src = ei;
    const int* dst = ei + N_EDGES;

    const float* w_rel[5], *b_rel[5], *w_root[5];
    for (int i = 0; i < 5; ++i) {
        w_rel[i]  = (const float*)d_in[4 + 3 * i];
        b_rel[i]  = (const float*)d_in[5 + 3 * i];
        w_root[i] = (const float*)d_in[6 + 3 * i];
    }
    const float* w_lin = (const float*)d_in[19];
    const float* b_lin = (const float*)d_in[20];
    float* out = (float*)d_out;

    // ---- workspace layout (16B-aligned sections) ----
    float* agg1    = (float*)d_ws;                     // 40000*7 fp32
    u16*   buf2    = (u16*)(agg1 + 280000);            // 40000*16 bf16 [agg|hin]
    u16*   buf3    = buf2 + 640000;                    // 40000*32
    u16*   buf4    = buf3 + 1280000;                   // 40000*64
    u16*   buf5    = buf4 + 2560000;                   // 40000*128
    float* pooled  = (float*)(buf5 + 5120000);         // 64*128 fp32
    int2*  csr_pair= (int2*)(pooled + N_GRAPHS * 128); // 640000 (src, w)
    int*   deg     = (int*)(csr_pair + N_EDGES);       // 40000
    int*   rs      = deg + N_NODES;                    // 40001
    int*   cursor  = rs + N_NODES + 1;                 // 40000
    int*   bsum    = cursor + N_NODES;                 // 64

    const int BLK = 256;
    const int EB = cdiv(N_EDGES, BLK);

    // ---- CSR build ----
    hipMemsetAsync(deg, 0, (size_t)N_NODES * sizeof(int), stream);
    hist_kernel<<<EB, BLK, 0, stream>>>(dst, deg);
    scan_part<<<40, 1024, 0, stream>>>(deg, rs, bsum);
    scan_add<<<40, 1024, 0, stream>>>(rs, bsum, cursor);
    scatter_kernel<<<EB, BLK, 0, stream>>>(src, dst, ea, cursor, csr_pair);

    // ---- layer 1: 7 -> 8 (fp32 in, bf16 out into buf2.hin) ----
    gather1<2><<<cdiv((long long)N_NODES * 32, BLK), BLK, 0, stream>>>(x, rs, csr_pair, agg1);
    node1<<<cdiv(N_NODES, 256), BLK, 0, stream>>>(agg1, x, w_rel[0], b_rel[0], w_root[0], buf2);

    // ---- layer 2: 8 -> 16 ----
    gather_bf16<0, 3, 16, 8, 16, 0><<<cdiv((long long)N_NODES * 8, BLK), BLK, 0, stream>>>(
        buf2, rs, csr_pair, buf2);
    node_mm<16, 16, 16, 4, 32, 16, false><<<dim3(cdiv(N_NODES, 256), 1), BLK, 0, stream>>>(
        buf2, w_rel[1], b_rel[1], w_root[1], buf3, nullptr, nullptr);

    // ---- layer 3: 16 -> 32 ----
    gather_bf16<1, 3, 32, 16, 32, 0><<<cdiv((long long)N_NODES * 16, BLK), BLK, 0, stream>>>(
        buf3, rs, csr_pair, buf3);
    node_mm<32, 32, 32, 4, 64, 32, false><<<dim3(cdiv(N_NODES, 128), 1), BLK, 0, stream>>>(
        buf3, w_rel[2], b_rel[2], w_root[2], buf4, nullptr, nullptr);

    // ---- layer 4: 32 -> 64 ----
    gather_bf16<2, 3, 64, 32, 64, 0><<<cdiv((long long)N_NODES * 32, BLK), BLK, 0, stream>>>(
        buf4, rs, csr_pair, buf4);
    node_mm<64, 64, 64, 8, 128, 64, false><<<dim3(cdiv(N_NODES, 128), 1), BLK, 0, stream>>>(
        buf4, w_rel[3], b_rel[3], w_root[3], buf5, nullptr, nullptr);

    // ---- layer 5: 64 -> 128, pooling fused ----
    gather_bf16<3, 3, 128, 64, 128, 0><<<cdiv((long long)N_NODES * 64, BLK), BLK, 0, stream>>>(
        buf5, rs, csr_pair, buf5);
    hipMemsetAsync(pooled, 0, (size_t)N_GRAPHS * 128 * sizeof(float), stream);
    node_mm<128, 128, 64, 8, 0, 0, true><<<dim3(cdiv(N_NODES, 128), 2), BLK, 0, stream>>>(
        buf5, w_rel[4], b_rel[4], w_root[4], nullptr, batch, pooled);

    // ---- classifier ----
    final_kernel<<<1, 128, 0, stream>>>(pooled, w_lin, b_lin, out);
}

// Round 5
// 254.138 us; speedup vs baseline: 2.7937x; 1.2473x over previous
//
#include <hip/hip_runtime.h>

#define N_NODES 40000
#define N_EDGES 640000
#define N_GRAPHS 64

typedef unsigned short u16;
typedef unsigned int u32;
typedef __attribute__((ext_vector_type(8))) short bf16x8;
typedef __attribute__((ext_vector_type(4))) float f32x4;

static inline int cdiv(long long a, int b) { return (int)((a + b - 1) / b); }

// ---------------- bf16 helpers (bf16 = top 16 bits of fp32) ----------------
__device__ __forceinline__ u16 f2bf(float f) {
    u32 u = __float_as_uint(f);
    u32 r = (u + 0x7fffu + ((u >> 16) & 1u)) >> 16;  // round-to-nearest-even
    return (u16)r;
}
__device__ __forceinline__ u32 packpair(float a, float b) {
    return (u32)f2bf(a) | ((u32)f2bf(b) << 16);
}
__device__ __forceinline__ void unpack8(uint4 q, float* o) {
    o[0] = __uint_as_float(q.x << 16); o[1] = __uint_as_float(q.x & 0xffff0000u);
    o[2] = __uint_as_float(q.y << 16); o[3] = __uint_as_float(q.y & 0xffff0000u);
    o[4] = __uint_as_float(q.z << 16); o[5] = __uint_as_float(q.z & 0xffff0000u);
    o[6] = __uint_as_float(q.w << 16); o[7] = __uint_as_float(q.w & 0xffff0000u);
}
__device__ __forceinline__ void fma4(float4& a, float s, const float4& w) {
    a.x = fmaf(s, w.x, a.x);
    a.y = fmaf(s, w.y, a.y);
    a.z = fmaf(s, w.z, a.z);
    a.w = fmaf(s, w.w, a.w);
}

// ---------------------------- CSR build ------------------------------------
__global__ __launch_bounds__(256) void hist_kernel(const int* __restrict__ dst,
                                                   int* __restrict__ deg) {
    int e = blockIdx.x * 256 + threadIdx.x;
    if (e < N_EDGES) atomicAdd(&deg[dst[e]], 1);
}

__global__ __launch_bounds__(1024) void scan_part(const int* __restrict__ deg,
                                                  int* __restrict__ row_start,
                                                  int* __restrict__ bsum) {
    __shared__ int wtot[16], woff[16];
    int tid = threadIdx.x;
    int i = blockIdx.x * 1024 + tid;
    int v = (i < N_NODES) ? deg[i] : 0;
    int lane = tid & 63, wid = tid >> 6;
    int inc = v;
    #pragma unroll
    for (int off = 1; off < 64; off <<= 1) {
        int y = __shfl_up(inc, off, 64);
        if (lane >= off) inc += y;
    }
    if (lane == 63) wtot[wid] = inc;
    __syncthreads();
    if (tid < 16) {
        int b = wtot[tid];
        #pragma unroll
        for (int off = 1; off < 16; off <<= 1) {
            int y = __shfl_up(b, off, 16);
            if ((tid & 15) >= off) b += y;
        }
        woff[tid] = b - wtot[tid];
        if (tid == 15) bsum[blockIdx.x] = b;
    }
    __syncthreads();
    if (i <= N_NODES) row_start[i] = woff[wid] + inc - v;
}

__global__ __launch_bounds__(1024) void scan_add(int* __restrict__ row_start,
                                                 const int* __restrict__ bsum,
                                                 int* __restrict__ cursor) {
    __shared__ int sbase;
    int tid = threadIdx.x;
    if (tid < 64) {
        int b = (tid < blockIdx.x) ? bsum[tid] : 0;
        #pragma unroll
        for (int off = 32; off; off >>= 1) b += __shfl_xor(b, off, 64);
        if (tid == 0) sbase = b;
    }
    __syncthreads();
    int i = blockIdx.x * 1024 + tid;
    if (i <= N_NODES) {
        int v = row_start[i] + sbase;
        row_start[i] = v;
        if (i < N_NODES) cursor[i] = v;
    }
}

__global__ __launch_bounds__(256) void scatter_kernel(const int* __restrict__ src,
                                                      const int* __restrict__ dst,
                                                      const float* __restrict__ ew,
                                                      int* __restrict__ cursor,
                                                      int2* __restrict__ csr_pair) {
    int e = blockIdx.x * 256 + threadIdx.x;
    if (e >= N_EDGES) return;
    int pos = atomicAdd(&cursor[dst[e]], 1);
    int2 q;
    q.x = src[e];
    q.y = __float_as_int(ew[e]);
    csr_pair[pos] = q;
}

// ---------------- weight packing into MFMA B-fragment layout ---------------
// B_pack[nt][ks][lane][j] = bf16( Wstk[ks*32 + (lane>>4)*8 + j][nt*16 + (lane&15)] )
// where Wstk = [w_rel (K/2 rows); w_root (K/2 rows)], FOUT cols.
__device__ __forceinline__ void pack_one(int idx, int K, int FOUT,
                                         const float* __restrict__ wrel,
                                         const float* __restrict__ wroot,
                                         u16* __restrict__ out) {
    int j = idx & 7;
    int lane = (idx >> 3) & 63;
    int ksnt = idx >> 9;
    int KS = K >> 5;
    int nt = ksnt / KS, ks = ksnt - nt * KS;
    int k = ks * 32 + (lane >> 4) * 8 + j;
    int col = nt * 16 + (lane & 15);
    float v = (k < K / 2) ? wrel[k * FOUT + col] : wroot[(k - K / 2) * FOUT + col];
    out[idx] = f2bf(v);
}

__global__ __launch_bounds__(256) void pack_weights(const float* __restrict__ wr3, const float* __restrict__ wo3,
                                                    const float* __restrict__ wr4, const float* __restrict__ wo4,
                                                    const float* __restrict__ wr5, const float* __restrict__ wo5,
                                                    u16* __restrict__ p3, u16* __restrict__ p4, u16* __restrict__ p5) {
    int tid = blockIdx.x * 256 + threadIdx.x;
    if (tid < 1024)        pack_one(tid,         32,  32,  wr3, wo3, p3);
    else if (tid < 5120)   pack_one(tid - 1024,  64,  64,  wr4, wo4, p4);
    else if (tid < 21504)  pack_one(tid - 5120, 128, 128,  wr5, wo5, p5);
}

// ---------------- layer-1 gather: fp32 x (FIN=7) ---------------------------
template<int SLOG>
__global__ __launch_bounds__(256) void gather1(const float* __restrict__ x,
                                               const int* __restrict__ rs,
                                               const int2* __restrict__ pair,
                                               float* __restrict__ agg) {
    const int S = 1 << SLOG;
    long long tid = (long long)blockIdx.x * 256 + threadIdx.x;
    int n = (int)(tid >> (3 + SLOG));
    if (n >= N_NODES) return;
    int sub = (int)(tid & ((8 << SLOG) - 1));
    int f = sub & 7;
    int half = sub >> 3;
    int beg = rs[n], end = rs[n + 1];
    float acc = 0.f;
    int p = beg + half;
    int s = 0; float w = 0.f;
    if (p < end) { int2 q = pair[p]; s = q.x; w = __int_as_float(q.y); }
    while (p < end) {
        float v = (f < 7) ? x[(long long)s * 7 + f] : 0.f;
        float wc = w;
        int pn = p + S;
        if (pn < end) { int2 q = pair[pn]; s = q.x; w = __int_as_float(q.y); }
        acc = fmaf(wc, v, acc);
        p = pn;
    }
    #pragma unroll
    for (int d = 8; d < (8 << SLOG); d <<= 1) acc += __shfl_xor(acc, d, 64);
    if (half == 0 && f < 7) agg[(long long)n * 7 + f] = acc;
}

// ---------------- bf16 gather: FIN = 8<<LOGF -------------------------------
template<int LOGF, int SLOG, int IN_STRIDE, int IN_OFF, int OUT_STRIDE, int OUT_OFF>
__global__ __launch_bounds__(256) void gather_bf16(const u16* __restrict__ hbuf,
                                                   const int* __restrict__ rs,
                                                   const int2* __restrict__ pair,
                                                   u16* __restrict__ obuf) {
    const int S = 1 << SLOG;
    long long tid = (long long)blockIdx.x * 256 + threadIdx.x;
    int n = (int)(tid >> (LOGF + SLOG));
    if (n >= N_NODES) return;
    int sub = (int)(tid & ((1 << (LOGF + SLOG)) - 1));
    int c = sub & ((1 << LOGF) - 1);
    int half = sub >> LOGF;
    const u16* base = hbuf + IN_OFF + c * 8;
    int beg = rs[n], end = rs[n + 1];
    float acc[8] = {0.f, 0.f, 0.f, 0.f, 0.f, 0.f, 0.f, 0.f};
    int p = beg + half;
    int s = 0; float w = 0.f;
    if (p < end) { int2 q = pair[p]; s = q.x; w = __int_as_float(q.y); }
    while (p < end) {
        uint4 rq = *(const uint4*)(base + (long long)s * IN_STRIDE);
        float wc = w;
        int pn = p + S;
        if (pn < end) { int2 q = pair[pn]; s = q.x; w = __int_as_float(q.y); }
        float tv[8];
        unpack8(rq, tv);
        #pragma unroll
        for (int j = 0; j < 8; ++j) acc[j] = fmaf(wc, tv[j], acc[j]);
        p = pn;
    }
    #pragma unroll
    for (int d = (1 << LOGF); d < (1 << (LOGF + SLOG)); d <<= 1) {
        #pragma unroll
        for (int j = 0; j < 8; ++j) acc[j] += __shfl_xor(acc[j], d, 64);
    }
    if (half == 0) {
        uint4 o;
        o.x = packpair(acc[0], acc[1]); o.y = packpair(acc[2], acc[3]);
        o.z = packpair(acc[4], acc[5]); o.w = packpair(acc[6], acc[7]);
        *(uint4*)(obuf + (long long)n * OUT_STRIDE + OUT_OFF + c * 8) = o;
    }
}

// ---------------- layer-1 node update (fp32 in, bf16 out) ------------------
__global__ __launch_bounds__(256) void node1(const float* __restrict__ agg,
                                             const float* __restrict__ x,
                                             const float* __restrict__ wr,
                                             const float* __restrict__ br,
                                             const float* __restrict__ wo,
                                             u16* __restrict__ obuf) {
    __shared__ float swr[56], swo[56], sb[8];
    if (threadIdx.x < 56) { swr[threadIdx.x] = wr[threadIdx.x]; swo[threadIdx.x] = wo[threadIdx.x]; }
    if (threadIdx.x < 8) sb[threadIdx.x] = br[threadIdx.x];
    __syncthreads();
    int n = blockIdx.x * 256 + threadIdx.x;
    if (n >= N_NODES) return;
    float a[7], h[7];
    #pragma unroll
    for (int i = 0; i < 7; ++i) {
        a[i] = agg[(long long)n * 7 + i];
        h[i] = x[(long long)n * 7 + i];
    }
    float o[8];
    #pragma unroll
    for (int j = 0; j < 8; ++j) {
        float s = sb[j];
        #pragma unroll
        for (int i = 0; i < 7; ++i) s = fmaf(a[i], swr[i * 8 + j], fmaf(h[i], swo[i * 8 + j], s));
        o[j] = s;
    }
    uint4 q;
    q.x = packpair(o[0], o[1]); q.y = packpair(o[2], o[3]);
    q.z = packpair(o[4], o[5]); q.w = packpair(o[6], o[7]);
    *(uint4*)(obuf + (long long)n * 16 + 8) = q;  // hin half of buf2
}

// ---------------- vector node update (kept for L2: K=16) -------------------
template<int K, int FOUT, int FO_TILE, int NT, int OUT_STRIDE, int OUT_OFF>
__global__ __launch_bounds__(256) void node_mm(const u16* __restrict__ abuf,
                                               const float* __restrict__ w_rel,
                                               const float* __restrict__ b_rel,
                                               const float* __restrict__ w_root,
                                               u16* __restrict__ obuf) {
    constexpr int FG = FO_TILE / 4;
    constexpr int SLOTS = 256 / FG;
    constexpr int BN = SLOTS * NT;
    __shared__ float sw[K][FO_TILE];
    for (int i = threadIdx.x; i < K * FO_TILE; i += 256) {
        int k = i / FO_TILE, j = i % FO_TILE;
        sw[k][j] = (k < K / 2) ? w_rel[k * FOUT + j]
                               : w_root[(k - K / 2) * FOUT + j];
    }
    __syncthreads();
    int fg = threadIdx.x % FG;
    int slot = threadIdx.x / FG;
    int n0 = blockIdx.x * BN + slot * NT;
    float4 bias = *(const float4*)&b_rel[fg * 4];
    float4 acc[NT];
    #pragma unroll
    for (int t = 0; t < NT; ++t) acc[t] = bias;

    #pragma unroll
    for (int kc = 0; kc < K / 8; ++kc) {
        float4 wv[8];
        #pragma unroll
        for (int k = 0; k < 8; ++k) wv[k] = *(const float4*)&sw[kc * 8 + k][fg * 4];
        #pragma unroll
        for (int t = 0; t < NT; ++t) {
            int n = n0 + t;
            if (n < N_NODES) {
                uint4 q = *(const uint4*)(abuf + (long long)n * K + kc * 8);
                float av[8];
                unpack8(q, av);
                #pragma unroll
                for (int k = 0; k < 8; ++k) fma4(acc[t], av[k], wv[k]);
            }
        }
    }
    #pragma unroll
    for (int t = 0; t < NT; ++t) {
        int n = n0 + t;
        if (n < N_NODES) {
            uint2 o;
            o.x = packpair(acc[t].x, acc[t].y);
            o.y = packpair(acc[t].z, acc[t].w);
            *(uint2*)(obuf + (long long)n * OUT_STRIDE + OUT_OFF + fg * 4) = o;
        }
    }
}

// ---------------- MFMA node update: [40000 x K] @ [K x FOUT] ---------------
// One wave per 16-node M-tile. A = abuf rows (bf16, [agg|hin]); B = packed
// fragments; D mapping (m89-verified): col = lane&15, row = (lane>>4)*4 + r.
template<int K, int FOUT, int OUT_STRIDE, int OUT_OFF, bool POOL>
__global__ __launch_bounds__(64) void node_mfma(const u16* __restrict__ abuf,
                                                const u16* __restrict__ bpack,
                                                const float* __restrict__ b_rel,
                                                u16* __restrict__ obuf,
                                                const int* __restrict__ batch,
                                                float* __restrict__ pooled) {
    constexpr int NT = FOUT / 16;
    constexpr int KS = K / 32;
    int lane = threadIdx.x;
    int tile = blockIdx.x;               // 0..2499
    int col = lane & 15;
    int node_a = tile * 16 + col;        // A-frag row for this lane
    int kgrp = (lane >> 4) * 8;

    f32x4 acc[NT];
    #pragma unroll
    for (int nt = 0; nt < NT; ++nt) {
        float bv = b_rel[nt * 16 + col];
        acc[nt] = (f32x4){bv, bv, bv, bv};
    }

    const u16* arow = abuf + (long long)node_a * K + kgrp;
    #pragma unroll
    for (int ks = 0; ks < KS; ++ks) {
        bf16x8 af = *(const bf16x8*)(arow + ks * 32);
        #pragma unroll
        for (int nt = 0; nt < NT; ++nt) {
            bf16x8 bf = *(const bf16x8*)(bpack + (((nt * KS + ks) << 6) + lane) * 8);
            acc[nt] = __builtin_amdgcn_mfma_f32_16x16x32_bf16(af, bf, acc[nt], 0, 0, 0);
        }
    }

    int row0 = tile * 16 + (lane >> 4) * 4;  // this lane's 4 D-rows
    if constexpr (!POOL) {
        #pragma unroll
        for (int nt = 0; nt < NT; ++nt)
            #pragma unroll
            for (int r = 0; r < 4; ++r)
                obuf[(long long)(row0 + r) * OUT_STRIDE + OUT_OFF + nt * 16 + col] =
                    f2bf(acc[nt][r]);
    } else {
        int b_first = batch[tile * 16];
        int b_last = batch[tile * 16 + 15];
        if (b_first == b_last) {
            // whole tile in one graph (common: sorted batch): reduce rows, 1 atomic/col
            #pragma unroll
            for (int nt = 0; nt < NT; ++nt) {
                float s = acc[nt][0] + acc[nt][1] + acc[nt][2] + acc[nt][3];
                s += __shfl_xor(s, 16, 64);
                s += __shfl_xor(s, 32, 64);
                if (lane < 16) atomicAdd(&pooled[b_first * FOUT + nt * 16 + col], s);
            }
        } else {
            #pragma unroll
            for (int r = 0; r < 4; ++r) {
                int g = batch[row0 + r];
                #pragma unroll
                for (int nt = 0; nt < NT; ++nt)
                    atomicAdd(&pooled[g * FOUT + nt * 16 + col], acc[nt][r]);
            }
        }
    }
}

// ---------------- classifier -----------------------------------------------
__global__ void final_kernel(const float* __restrict__ pooled,
                             const float* __restrict__ w_lin,
                             const float* __restrict__ b_lin,
                             float* __restrict__ out) {
    int tid = threadIdx.x;
    int g = tid >> 1;
    int c = tid & 1;
    float acc = b_lin[c];
    #pragma unroll 8
    for (int fi = 0; fi < 128; ++fi)
        acc += pooled[g * 128 + fi] * w_lin[fi * 2 + c];
    out[g * 2 + c] = acc;
}

extern "C" void kernel_launch(void* const* d_in, const int* in_sizes, int n_in,
                              void* d_out, int out_size, void* d_ws, size_t ws_size,
                              hipStream_t stream) {
    const float* x     = (const float*)d_in[0];
    const int*   ei    = (const int*)d_in[1];
    const float* ea    = (const float*)d_in[2];
    const int*   batch = (const int*)d_in[3];
    const int* src = ei;
    const int* dst = ei + N_EDGES;

    const float* w_rel[5], *b_rel[5], *w_root[5];
    for (int i = 0; i < 5; ++i) {
        w_rel[i]  = (const float*)d_in[4 + 3 * i];
        b_rel[i]  = (const float*)d_in[5 + 3 * i];
        w_root[i] = (const float*)d_in[6 + 3 * i];
    }
    const float* w_lin = (const float*)d_in[19];
    const float* b_lin = (const float*)d_in[20];
    float* out = (float*)d_out;

    // ---- workspace layout (16B-aligned sections) ----
    float* agg1    = (float*)d_ws;                     // 280000 f32
    u16*   buf2    = (u16*)(agg1 + 280000);            // 40000*16 bf16 [agg|hin]
    u16*   buf3    = buf2 + 640000;                    // 40000*32
    u16*   buf4    = buf3 + 1280000;                   // 40000*64
    u16*   buf5    = buf4 + 2560000;                   // 40000*128
    float* pooled  = (float*)(buf5 + 5120000);         // 64*128 fp32
    u16*   p3      = (u16*)(pooled + N_GRAPHS * 128);  // 1024
    u16*   p4      = p3 + 1024;                        // 4096
    u16*   p5      = p4 + 4096;                        // 16384
    int2*  csr_pair= (int2*)(p5 + 16384);              // 640000 (src, w)
    int*   deg     = (int*)(csr_pair + N_EDGES);       // 40000
    int*   rs      = deg + N_NODES;                    // 40001
    int*   cursor  = rs + N_NODES + 1;                 // 40000
    int*   bsum    = cursor + N_NODES;                 // 64

    const int BLK = 256;
    const int EB = cdiv(N_EDGES, BLK);

    // ---- weight packing + CSR build ----
    pack_weights<<<84, BLK, 0, stream>>>(w_rel[2], w_root[2], w_rel[3], w_root[3],
                                         w_rel[4], w_root[4], p3, p4, p5);
    hipMemsetAsync(deg, 0, (size_t)N_NODES * sizeof(int), stream);
    hist_kernel<<<EB, BLK, 0, stream>>>(dst, deg);
    scan_part<<<40, 1024, 0, stream>>>(deg, rs, bsum);
    scan_add<<<40, 1024, 0, stream>>>(rs, bsum, cursor);
    scatter_kernel<<<EB, BLK, 0, stream>>>(src, dst, ea, cursor, csr_pair);

    // ---- layer 1: 7 -> 8 (fp32 in, bf16 out into buf2.hin) ----
    gather1<2><<<cdiv((long long)N_NODES * 32, BLK), BLK, 0, stream>>>(x, rs, csr_pair, agg1);
    node1<<<cdiv(N_NODES, 256), BLK, 0, stream>>>(agg1, x, w_rel[0], b_rel[0], w_root[0], buf2);

    // ---- layer 2: 8 -> 16 (vector) ----
    gather_bf16<0, 3, 16, 8, 16, 0><<<cdiv((long long)N_NODES * 8, BLK), BLK, 0, stream>>>(
        buf2, rs, csr_pair, buf2);
    node_mm<16, 16, 16, 4, 32, 16><<<cdiv(N_NODES, 256), BLK, 0, stream>>>(
        buf2, w_rel[1], b_rel[1], w_root[1], buf3);

    // ---- layer 3: 16 -> 32 (MFMA) ----
    gather_bf16<1, 3, 32, 16, 32, 0><<<cdiv((long long)N_NODES * 16, BLK), BLK, 0, stream>>>(
        buf3, rs, csr_pair, buf3);
    node_mfma<32, 32, 64, 32, false><<<2500, 64, 0, stream>>>(
        buf3, p3, b_rel[2], buf4, nullptr, nullptr);

    // ---- layer 4: 32 -> 64 (MFMA) ----
    gather_bf16<2, 3, 64, 32, 64, 0><<<cdiv((long long)N_NODES * 32, BLK), BLK, 0, stream>>>(
        buf4, rs, csr_pair, buf4);
    node_mfma<64, 64, 128, 64, false><<<2500, 64, 0, stream>>>(
        buf4, p4, b_rel[3], buf5, nullptr, nullptr);

    // ---- layer 5: 64 -> 128 (MFMA, pooling fused) ----
    gather_bf16<3, 3, 128, 64, 128, 0><<<cdiv((long long)N_NODES * 64, BLK), BLK, 0, stream>>>(
        buf5, rs, csr_pair, buf5);
    hipMemsetAsync(pooled, 0, (size_t)N_GRAPHS * 128 * sizeof(float), stream);
    node_mfma<128, 128, 0, 0, true><<<2500, 64, 0, stream>>>(
        buf5, p5, b_rel[4], nullptr, batch, pooled);

    // ---- classifier ----
    final_kernel<<<1, 128, 0, stream>>>(pooled, w_lin, b_lin, out);
}